// Round 1
// baseline (1128.235 us; speedup 1.0000x reference)
//
#include <hip/hip_runtime.h>

// LightGCN propagation on MI355X (gfx950).
//   h_{k+1}[r,:] = sum_{e: row[e]==r} val[e] * h_k[col[e],:]   D=32
//   out = (x + h1 + h2 + h3) / 4
//
// Round 10: top-5 rocprof shows only harness 268MB fills (42.7+ us) -> all
// 9 of our kernels are <43 us; build pipeline (~90 us) is ~40% of runtime.
// The full per-row sort (bucket_sort + row_ptr CSR) existed only to feed a
// register-accumulating SpMM. Replaced:
//  * SpMM is now bucket-per-block: LDS fp32 accumulator acc[128][33]
//    (odd stride -> ~2-way random bank conflict, free), ds_add_f32 atomics,
//    epilogue writes 128 contiguous rows. bucket_sort + row_ptr DELETED
//    (-25.6 MB traffic, -1 kernel).
//  * scatter now stages the 4096-edge chunk in LDS in bucket order
//    (recs 32KB + dest 16KB) so global stores walk sorted positions:
//    destinations are run-contiguous (avg 42 B runs, ~12 txn/wave vs 64
//    scattered 8 B stores) and address-ordered for L2 merge.
// Gather stays bf16 (row = 64 B = 1 line); x/out/accum stay fp32.

#define NN 100000
#define NE 1600000
#define DD 32
#define CHUNK 4096
#define NCHUNK ((NE + CHUNK - 1) / CHUNK)   // 391
#define BROWS 128
#define NBKT ((NN + BROWS - 1) / BROWS)     // 782

__device__ __forceinline__ unsigned f2bf(float f) {
    unsigned u = __float_as_uint(f);
    return (u + 0x7fffu + ((u >> 16) & 1u)) >> 16;   // RNE
}

// ---- pass 1: bucket histogram --------------------------------------------

__global__ __launch_bounds__(1024) void hist_kernel(
    const int* __restrict__ row, int* __restrict__ bucket_tot)
{
    __shared__ int cnt[NBKT];
    const int tid = threadIdx.x;
    const int start = blockIdx.x * CHUNK;
    const int n = min(CHUNK, NE - start);
    for (int k = tid; k < NBKT; k += 1024) cnt[k] = 0;
    __syncthreads();
    #pragma unroll
    for (int k = 0; k < CHUNK / 1024; k++) {
        int j = k * 1024 + tid;
        if (j < n) atomicAdd(&cnt[row[start + j] >> 7], 1);
    }
    __syncthreads();
    for (int k = tid; k < NBKT; k += 1024)
        if (cnt[k]) atomicAdd(&bucket_tot[k], cnt[k]);
}

// ---- pass 2: exclusive scan of 782 bucket totals -> base + cursors -------

__global__ __launch_bounds__(1024) void scan_kernel(
    const int* __restrict__ tot, int* __restrict__ bucketbase,
    int* __restrict__ cursor)
{
    const int tid = threadIdx.x;
    int v = (tid < NBKT) ? tot[tid] : 0;
    int lane = tid & 63, w = tid >> 6;          // 16 waves
    int x = v;
    #pragma unroll
    for (int off = 1; off < 64; off <<= 1) {
        int y = __shfl_up(x, off, 64);
        if (lane >= off) x += y;
    }
    __shared__ int wt[16];
    if (lane == 63) wt[w] = x;
    __syncthreads();
    if (w == 0 && lane < 16) {
        int y = wt[lane];
        #pragma unroll
        for (int off = 1; off < 16; off <<= 1) {
            int z = __shfl_up(y, off, 16);
            if ((lane & 15) >= off) y += z;
        }
        wt[lane] = y;                            // inclusive wave totals
    }
    __syncthreads();
    int wo = (w > 0) ? wt[w - 1] : 0;
    int excl = x + wo - v;
    if (tid < NBKT) { bucketbase[tid] = excl; cursor[tid] = excl; }
    if (tid == NBKT) { bucketbase[NBKT] = NE; }
}

// ---- pass 3: multisplit scatter, LDS-staged for coalesced stores ---------
// record: ((row & 127) << 17) | col   (col < 2^17), val bits in .y

__global__ __launch_bounds__(1024) void scatter_kernel(
    const int* __restrict__ row, const int* __restrict__ col,
    const float* __restrict__ val, int* __restrict__ cursor,
    int2* __restrict__ tmp)
{
    __shared__ int cnt[NBKT];      // 3.1 KB
    __shared__ int lbase[NBKT];    // 3.1 KB  chunk-local exclusive scan
    __shared__ int gofs[NBKT];     // 3.1 KB  global base per bucket
    __shared__ int wt[16];
    __shared__ int2 recs[CHUNK];   // 32 KB   records in bucket order
    __shared__ int dest[CHUNK];    // 16 KB   global dst per sorted position
    const int tid = threadIdx.x;
    const int start = blockIdx.x * CHUNK;
    const int n = min(CHUNK, NE - start);
    for (int k = tid; k < NBKT; k += 1024) cnt[k] = 0;
    __syncthreads();

    int rrow[CHUNK / 1024], rcol[CHUNK / 1024], rank[CHUNK / 1024];
    float rval[CHUNK / 1024];
    #pragma unroll
    for (int k = 0; k < CHUNK / 1024; k++) {
        int j = k * 1024 + tid;
        if (j < n) {
            int r = row[start + j];
            rrow[k] = r;
            rcol[k] = col[start + j];
            rval[k] = val[start + j];
            rank[k] = atomicAdd(&cnt[r >> 7], 1);
        } else {
            rrow[k] = -1;
        }
    }
    __syncthreads();

    // block-level exclusive scan of cnt -> lbase; global cursor -> gofs
    int v = (tid < NBKT) ? cnt[tid] : 0;
    {
        int lane = tid & 63, w = tid >> 6;
        int x = v;
        #pragma unroll
        for (int off = 1; off < 64; off <<= 1) {
            int y = __shfl_up(x, off, 64);
            if (lane >= off) x += y;
        }
        if (lane == 63) wt[w] = x;
        __syncthreads();
        if (w == 0 && lane < 16) {
            int y = wt[lane];
            #pragma unroll
            for (int off = 1; off < 16; off <<= 1) {
                int z = __shfl_up(y, off, 16);
                if ((lane & 15) >= off) y += z;
            }
            wt[lane] = y;
        }
        __syncthreads();
        int excl = x + ((w > 0) ? wt[w - 1] : 0) - v;
        if (tid < NBKT) {
            lbase[tid] = excl;
            gofs[tid] = v ? atomicAdd(&cursor[tid], v) : 0;
        }
    }
    __syncthreads();

    #pragma unroll
    for (int k = 0; k < CHUNK / 1024; k++) {
        if (rrow[k] >= 0) {
            int b = rrow[k] >> 7;
            int p = lbase[b] + rank[k];
            recs[p] = make_int2(((rrow[k] & 127) << 17) | rcol[k],
                                __float_as_int(rval[k]));
            dest[p] = gofs[b] + rank[k];
        }
    }
    __syncthreads();

    for (int p = tid; p < n; p += 1024)        // run-contiguous stores
        tmp[dest[p]] = recs[p];
}

// ---- x -> bf16 table (feat 2k in low half, 2k+1 in high half) ------------

__global__ __launch_bounds__(256) void cvt_kernel(
    const float2* __restrict__ xin2, unsigned* __restrict__ hb)
{
    int j = blockIdx.x * 256 + threadIdx.x;      // word index, NN*DD/2 words
    if (j >= NN * DD / 2) return;
    float2 f = xin2[j];
    hb[j] = f2bf(f.x) | (f2bf(f.y) << 16);
}

// ---- SpMM: one bucket (128 rows) per block, LDS fp32 accumulation --------
// 512 threads = 128 four-lane groups; lane t owns feats [8t, 8t+8).
// Edges consumed straight from bucket-grouped tmp (unsorted within bucket);
// collisions handled by ds_add_f32. Stride 33 -> random-row atomics spread
// across banks (~2-way, free).
// MODE 0: houtb = bf16(A x)  ; out  = x + A x
// MODE 1: houtb = bf16(A h)  ; out += A h
// MODE 2: out = (out + A h) * 0.25

template <int MODE>
__global__ __launch_bounds__(512) void spmm_kernel(
    const int* __restrict__ bucketbase, const int2* __restrict__ tmp,
    const uint4* __restrict__ hb4,               // bf16 table, 4 uint4/row
    uint4* __restrict__ houtb4,                  // next bf16 table
    const float4* __restrict__ xin4, float4* __restrict__ out4)
{
    __shared__ float acc[BROWS][DD + 1];         // 16.9 KB, odd stride
    const int tid = threadIdx.x;
    const int b = blockIdx.x;
    const int s = bucketbase[b];
    const int e = bucketbase[b + 1];

    for (int k = tid; k < BROWS * (DD + 1); k += 512)
        (&acc[0][0])[k] = 0.f;
    __syncthreads();

    const int t = tid & 3;
    const int g = tid >> 2;                      // group id = 0..127

#define GACC(REC, W)                                                       \
    do {                                                                   \
        int r_ = (REC).x >> 17;                                            \
        float v_ = __int_as_float((REC).y);                                \
        float* a_ = &acc[r_][t * 8];                                       \
        atomicAdd(a_ + 0, v_ * __uint_as_float((W).x << 16));              \
        atomicAdd(a_ + 1, v_ * __uint_as_float((W).x & 0xffff0000u));      \
        atomicAdd(a_ + 2, v_ * __uint_as_float((W).y << 16));              \
        atomicAdd(a_ + 3, v_ * __uint_as_float((W).y & 0xffff0000u));      \
        atomicAdd(a_ + 4, v_ * __uint_as_float((W).z << 16));              \
        atomicAdd(a_ + 5, v_ * __uint_as_float((W).z & 0xffff0000u));      \
        atomicAdd(a_ + 6, v_ * __uint_as_float((W).w << 16));              \
        atomicAdd(a_ + 7, v_ * __uint_as_float((W).w & 0xffff0000u));      \
    } while (0)

    int i = s + g;
    for (; i + 128 < e; i += 256) {              // 2 edges in flight/group
        int2 r0 = tmp[i];
        int2 r1 = tmp[i + 128];
        uint4 w0 = hb4[(r0.x & 0x1FFFF) * 4 + t];
        uint4 w1 = hb4[(r1.x & 0x1FFFF) * 4 + t];
        GACC(r0, w0);
        GACC(r1, w1);
    }
    if (i < e) {
        int2 r0 = tmp[i];
        uint4 w0 = hb4[(r0.x & 0x1FFFF) * 4 + t];
        GACC(r0, w0);
    }
#undef GACC
    __syncthreads();

    // epilogue: group g owns row b*128+g, lane t feats [8t, 8t+8)
    const int rr = b * BROWS + g;
    if (rr >= NN) return;
    float a0 = acc[g][t * 8 + 0];
    float a1 = acc[g][t * 8 + 1];
    float a2 = acc[g][t * 8 + 2];
    float a3 = acc[g][t * 8 + 3];
    float a4 = acc[g][t * 8 + 4];
    float a5 = acc[g][t * 8 + 5];
    float a6 = acc[g][t * 8 + 6];
    float a7 = acc[g][t * 8 + 7];

    if (MODE == 0 || MODE == 1) {
        uint4 p;
        p.x = f2bf(a0) | (f2bf(a1) << 16);
        p.y = f2bf(a2) | (f2bf(a3) << 16);
        p.z = f2bf(a4) | (f2bf(a5) << 16);
        p.w = f2bf(a6) | (f2bf(a7) << 16);
        houtb4[rr * 4 + t] = p;
    }
    const int o = rr * 8 + t * 2;                // two float4s per lane
    float4 lo, hi;
    if (MODE == 0) {
        float4 x0 = xin4[o], x1 = xin4[o + 1];
        lo = make_float4(x0.x + a0, x0.y + a1, x0.z + a2, x0.w + a3);
        hi = make_float4(x1.x + a4, x1.y + a5, x1.z + a6, x1.w + a7);
    } else if (MODE == 1) {
        float4 o0 = out4[o], o1 = out4[o + 1];
        lo = make_float4(o0.x + a0, o0.y + a1, o0.z + a2, o0.w + a3);
        hi = make_float4(o1.x + a4, o1.y + a5, o1.z + a6, o1.w + a7);
    } else {
        float4 o0 = out4[o], o1 = out4[o + 1];
        lo = make_float4((o0.x + a0) * 0.25f, (o0.y + a1) * 0.25f,
                         (o0.z + a2) * 0.25f, (o0.w + a3) * 0.25f);
        hi = make_float4((o1.x + a4) * 0.25f, (o1.y + a5) * 0.25f,
                         (o1.z + a6) * 0.25f, (o1.w + a7) * 0.25f);
    }
    out4[o] = lo;
    out4[o + 1] = hi;
}

// ---- launch ---------------------------------------------------------------

extern "C" void kernel_launch(void* const* d_in, const int* in_sizes, int n_in,
                              void* d_out, int out_size, void* d_ws, size_t ws_size,
                              hipStream_t stream) {
    const int*   edge_row = (const int*)d_in[0];
    const int*   edge_col = (const int*)d_in[1];
    const float* edge_val = (const float*)d_in[2];
    const float* x        = (const float*)d_in[3];
    float* out = (float*)d_out;

    char* ws = (char*)d_ws;
    int*  bucket_tot = (int*)ws;                          ws += 4096;
    int*  bucketbase = (int*)ws;                          ws += 4096;
    int*  cursor     = (int*)ws;                          ws += 4096;
    int2* tmp        = (int2*)ws;                         ws += (size_t)NE * 8 + 64;  // 12.8 MB
    unsigned* hb0    = (unsigned*)ws;                     ws += (size_t)NN * DD * 2;  // 6.4 MB bf16
    unsigned* hb1    = (unsigned*)ws;                     ws += (size_t)NN * DD * 2;  // 6.4 MB bf16

    hipMemsetAsync(bucket_tot, 0, NBKT * sizeof(int), stream);
    hist_kernel   <<<NCHUNK, 1024, 0, stream>>>(edge_row, bucket_tot);
    scan_kernel   <<<1, 1024, 0, stream>>>(bucket_tot, bucketbase, cursor);
    scatter_kernel<<<NCHUNK, 1024, 0, stream>>>(edge_row, edge_col, edge_val,
                                                cursor, tmp);
    cvt_kernel    <<<(NN * DD / 2 + 255) / 256, 256, 0, stream>>>(
                    (const float2*)x, hb0);

    spmm_kernel<0><<<NBKT, 512, 0, stream>>>(bucketbase, tmp,
        (const uint4*)hb0, (uint4*)hb1, (const float4*)x, (float4*)out);
    spmm_kernel<1><<<NBKT, 512, 0, stream>>>(bucketbase, tmp,
        (const uint4*)hb1, (uint4*)hb0, (const float4*)x, (float4*)out);
    spmm_kernel<2><<<NBKT, 512, 0, stream>>>(bucketbase, tmp,
        (const uint4*)hb0, (uint4*)hb1, (const float4*)x, (float4*)out);
}

// Round 2
// 245.704 us; speedup vs baseline: 4.5918x; 4.5918x over previous
//
#include <hip/hip_runtime.h>

// LightGCN propagation on MI355X (gfx950).
//   h_{k+1}[r,:] = sum_{e: row[e]==r} val[e] * h_k[col[e],:]   D=32
//   out = (x + h1 + h2 + h3) / 4
//
// Round 11: R10 post-mortem -- LDS fp32 atomics in spmm ran at ~1 lane-op/
// cy/CU (342 us/layer, VALUBusy 1.4%): register accumulation over sorted
// edges is the only fast spmm; restored. Non-spmm time measured ~100 us,
// dominated by scatter (~75 us) whose only expensive op is 306k cross-XCD
// global atomicAdd(cursor) RMWs on 49 cache lines. Replaced with
// deterministic placement: hist writes per-(chunk,bucket) counts H[c][b]
// (1.2 MB coalesced), scan_chunks makes exclusive per-bucket prefixes P,
// scatter computes dest = bucketbase[b] + P[chunk][b] + local_rank.
// ZERO global atomics anywhere. LDS-staged run-contiguous stores kept.
// SpMM gather pipeline deepened 4 -> 8 edges in flight (L2-miss latency
// bound; FETCH 64 MB/layer from 6.4 MB table thrashing 4 MB/XCD L2).

#define NN 100000
#define NE 1600000
#define DD 32
#define CHUNK 4096
#define NCHUNK ((NE + CHUNK - 1) / CHUNK)   // 391
#define BROWS 128
#define NBKT ((NN + BROWS - 1) / BROWS)     // 782

__device__ __forceinline__ unsigned f2bf(float f) {
    unsigned u = __float_as_uint(f);
    return (u + 0x7fffu + ((u >> 16) & 1u)) >> 16;   // RNE
}

// ---- pass 1: per-chunk bucket histogram matrix H[c][b] -------------------

__global__ __launch_bounds__(1024) void hist_kernel(
    const int* __restrict__ row, int* __restrict__ H)
{
    __shared__ int cnt[NBKT];
    const int tid = threadIdx.x;
    const int start = blockIdx.x * CHUNK;
    const int n = min(CHUNK, NE - start);
    for (int k = tid; k < NBKT; k += 1024) cnt[k] = 0;
    __syncthreads();
    #pragma unroll
    for (int k = 0; k < CHUNK / 1024; k++) {
        int j = k * 1024 + tid;
        if (j < n) atomicAdd(&cnt[row[start + j] >> 7], 1);
    }
    __syncthreads();
    int* Hrow = H + (size_t)blockIdx.x * NBKT;
    for (int k = tid; k < NBKT; k += 1024) Hrow[k] = cnt[k];   // coalesced
}

// ---- pass 2a: per-bucket exclusive scan over chunks (columns of H) -------
// Thread owns bucket b; iteration c loads H[c][b0..] coalesced across the
// wave. Loads (restrict, separate dst array) pipeline; dep chain is adds.

__global__ __launch_bounds__(128) void scan_chunks_kernel(
    const int* __restrict__ H, int* __restrict__ P, int* __restrict__ tot)
{
    int b = blockIdx.x * 128 + threadIdx.x;
    if (b >= NBKT) return;
    int run = 0;
    #pragma unroll 4
    for (int c = 0; c < NCHUNK; c++) {
        int v = H[(size_t)c * NBKT + b];
        P[(size_t)c * NBKT + b] = run;
        run += v;
    }
    tot[b] = run;
}

// ---- pass 2b: exclusive scan of 782 bucket totals ------------------------

__global__ __launch_bounds__(1024) void scan_buckets_kernel(
    const int* __restrict__ tot, int* __restrict__ bucketbase,
    int* __restrict__ row_ptr)
{
    const int tid = threadIdx.x;
    int v = (tid < NBKT) ? tot[tid] : 0;
    int lane = tid & 63, w = tid >> 6;          // 16 waves
    int x = v;
    #pragma unroll
    for (int off = 1; off < 64; off <<= 1) {
        int y = __shfl_up(x, off, 64);
        if (lane >= off) x += y;
    }
    __shared__ int wt[16];
    if (lane == 63) wt[w] = x;
    __syncthreads();
    if (w == 0 && lane < 16) {
        int y = wt[lane];
        #pragma unroll
        for (int off = 1; off < 16; off <<= 1) {
            int z = __shfl_up(y, off, 16);
            if ((lane & 15) >= off) y += z;
        }
        wt[lane] = y;                            // inclusive wave totals
    }
    __syncthreads();
    int wo = (w > 0) ? wt[w - 1] : 0;
    int excl = x + wo - v;
    if (tid < NBKT) bucketbase[tid] = excl;
    if (tid == NBKT) { bucketbase[NBKT] = NE; row_ptr[NN] = NE; }
}

// ---- pass 3: multisplit scatter, deterministic dest, LDS-staged stores ---
// record: ((row & 127) << 17) | col   (col < 2^17), val bits in .y

__global__ __launch_bounds__(1024) void scatter_kernel(
    const int* __restrict__ row, const int* __restrict__ col,
    const float* __restrict__ val, const int* __restrict__ bucketbase,
    const int* __restrict__ P, int2* __restrict__ tmp)
{
    __shared__ int cnt[NBKT];      // 3.1 KB
    __shared__ int lbase[NBKT];    // 3.1 KB  chunk-local exclusive scan
    __shared__ int gofs[NBKT];     // 3.1 KB  global base per bucket
    __shared__ int wt[16];
    __shared__ int2 recs[CHUNK];   // 32 KB   records in bucket order
    __shared__ int dest[CHUNK];    // 16 KB   global dst per sorted position
    const int tid = threadIdx.x;
    const int start = blockIdx.x * CHUNK;
    const int n = min(CHUNK, NE - start);
    for (int k = tid; k < NBKT; k += 1024) cnt[k] = 0;
    __syncthreads();

    int rrow[CHUNK / 1024], rcol[CHUNK / 1024], rank[CHUNK / 1024];
    float rval[CHUNK / 1024];
    #pragma unroll
    for (int k = 0; k < CHUNK / 1024; k++) {
        int j = k * 1024 + tid;
        if (j < n) {
            int r = row[start + j];
            rrow[k] = r;
            rcol[k] = col[start + j];
            rval[k] = val[start + j];
            rank[k] = atomicAdd(&cnt[r >> 7], 1);
        } else {
            rrow[k] = -1;
        }
    }
    __syncthreads();

    // block-level exclusive scan of cnt -> lbase; deterministic gofs
    int v = (tid < NBKT) ? cnt[tid] : 0;
    {
        int lane = tid & 63, w = tid >> 6;
        int x = v;
        #pragma unroll
        for (int off = 1; off < 64; off <<= 1) {
            int y = __shfl_up(x, off, 64);
            if (lane >= off) x += y;
        }
        if (lane == 63) wt[w] = x;
        __syncthreads();
        if (w == 0 && lane < 16) {
            int y = wt[lane];
            #pragma unroll
            for (int off = 1; off < 16; off <<= 1) {
                int z = __shfl_up(y, off, 16);
                if ((lane & 15) >= off) y += z;
            }
            wt[lane] = y;
        }
        __syncthreads();
        int excl = x + ((w > 0) ? wt[w - 1] : 0) - v;
        if (tid < NBKT) {
            lbase[tid] = excl;
            gofs[tid] = bucketbase[tid] + P[(size_t)blockIdx.x * NBKT + tid];
        }
    }
    __syncthreads();

    #pragma unroll
    for (int k = 0; k < CHUNK / 1024; k++) {
        if (rrow[k] >= 0) {
            int b = rrow[k] >> 7;
            int p = lbase[b] + rank[k];
            recs[p] = make_int2(((rrow[k] & 127) << 17) | rcol[k],
                                __float_as_int(rval[k]));
            dest[p] = gofs[b] + rank[k];
        }
    }
    __syncthreads();

    for (int p = tid; p < n; p += 1024)        // run-contiguous stores
        tmp[dest[p]] = recs[p];
}

// ---- pass 4: per-bucket row sort -> CSR row_ptr + clean (col,val) --------

__global__ __launch_bounds__(512) void bucket_sort_kernel(
    const int* __restrict__ bucketbase, const int2* __restrict__ tmp,
    int* __restrict__ row_ptr, int2* __restrict__ edges)
{
    __shared__ int cnt[BROWS];
    __shared__ int cur[BROWS];
    __shared__ int wt2[2];
    const int tid = threadIdx.x;
    const int b   = blockIdx.x;
    const int s   = bucketbase[b];
    const int e   = bucketbase[b + 1];

    if (tid < BROWS) cnt[tid] = 0;
    __syncthreads();

    int2 rc[5];
    #pragma unroll
    for (int k = 0; k < 5; k++) {
        int j = s + k * 512 + tid;
        rc[k] = (j < e) ? tmp[j] : make_int2(-1, 0);
        if (rc[k].x >= 0) atomicAdd(&cnt[rc[k].x >> 17], 1);
    }
    for (int j = s + 5 * 512 + tid; j < e; j += 512)       // overflow (rare)
        atomicAdd(&cnt[tmp[j].x >> 17], 1);
    __syncthreads();

    int v = 0, x = 0;
    if (tid < BROWS) {
        v = cnt[tid];
        int lane = tid & 63;
        x = v;
        #pragma unroll
        for (int off = 1; off < 64; off <<= 1) {
            int y = __shfl_up(x, off, 64);
            if (lane >= off) x += y;
        }
        if (lane == 63) wt2[tid >> 6] = x;
    }
    __syncthreads();
    if (tid < BROWS) {
        int excl = x + ((tid >> 6) ? wt2[0] : 0) - v;
        cur[tid] = excl;
        int r = b * BROWS + tid;
        if (r < NN) row_ptr[r] = s + excl;
    }
    __syncthreads();

    #pragma unroll
    for (int k = 0; k < 5; k++) {
        if (rc[k].x >= 0) {
            int pos = s + atomicAdd(&cur[rc[k].x >> 17], 1);
            edges[pos] = make_int2(rc[k].x & 0x1FFFF, rc[k].y);
        }
    }
    for (int j = s + 5 * 512 + tid; j < e; j += 512) {     // overflow (rare)
        int2 rec = tmp[j];
        int pos = s + atomicAdd(&cur[rec.x >> 17], 1);
        edges[pos] = make_int2(rec.x & 0x1FFFF, rec.y);
    }
}

// ---- x -> bf16 table (feat 2k in low half, 2k+1 in high half) ------------

__global__ __launch_bounds__(256) void cvt_kernel(
    const float2* __restrict__ xin2, unsigned* __restrict__ hb)
{
    int j = blockIdx.x * 256 + threadIdx.x;      // word index, NN*DD/2 words
    if (j >= NN * DD / 2) return;
    float2 f = xin2[j];
    hb[j] = f2bf(f.x) | (f2bf(f.y) << 16);
}

// ---- SpMM: 4-lane group per row, bf16 gather (64 B row = 1 line) ---------
// Lane t in [0,4) owns feats [8t, 8t+8) = one uint4 of the bf16 row.
// 8 gathers in flight (gather-latency bound: table thrashes 4MB/XCD L2).
// MODE 0: houtb = bf16(A x)  ; out  = x + A x
// MODE 1: houtb = bf16(A h)  ; out += A h
// MODE 2: out = (out + A h) * 0.25

template <int MODE>
__global__ __launch_bounds__(256) void spmm_kernel(
    const int* __restrict__ row_ptr, const int2* __restrict__ edges,
    const uint4* __restrict__ hb4,               // bf16 table, 4 uint4/row
    uint4* __restrict__ houtb4,                  // next bf16 table
    const float4* __restrict__ xin4, float4* __restrict__ out4)
{
    const int g = blockIdx.x * 64 + (threadIdx.x >> 2);   // row
    if (g >= NN) return;
    const int t = threadIdx.x & 3;
    const int s = row_ptr[g];
    const int e = row_ptr[g + 1];

    float acc[8] = {0.f, 0.f, 0.f, 0.f, 0.f, 0.f, 0.f, 0.f};

#define ACC8(W, V)                                                         \
    do {                                                                   \
        acc[0] += (V) * __uint_as_float((W).x << 16);                      \
        acc[1] += (V) * __uint_as_float((W).x & 0xffff0000u);              \
        acc[2] += (V) * __uint_as_float((W).y << 16);                      \
        acc[3] += (V) * __uint_as_float((W).y & 0xffff0000u);              \
        acc[4] += (V) * __uint_as_float((W).z << 16);                      \
        acc[5] += (V) * __uint_as_float((W).z & 0xffff0000u);              \
        acc[6] += (V) * __uint_as_float((W).w << 16);                      \
        acc[7] += (V) * __uint_as_float((W).w & 0xffff0000u);              \
    } while (0)

    int i = s;
    for (; i + 8 <= e; i += 8) {                 // 8 gathers in flight
        int2 a0 = edges[i];
        int2 a1 = edges[i + 1];
        int2 a2 = edges[i + 2];
        int2 a3 = edges[i + 3];
        int2 a4 = edges[i + 4];
        int2 a5 = edges[i + 5];
        int2 a6 = edges[i + 6];
        int2 a7 = edges[i + 7];
        uint4 w0 = hb4[a0.x * 4 + t];
        uint4 w1 = hb4[a1.x * 4 + t];
        uint4 w2 = hb4[a2.x * 4 + t];
        uint4 w3 = hb4[a3.x * 4 + t];
        uint4 w4 = hb4[a4.x * 4 + t];
        uint4 w5 = hb4[a5.x * 4 + t];
        uint4 w6 = hb4[a6.x * 4 + t];
        uint4 w7 = hb4[a7.x * 4 + t];
        ACC8(w0, __int_as_float(a0.y)); ACC8(w1, __int_as_float(a1.y));
        ACC8(w2, __int_as_float(a2.y)); ACC8(w3, __int_as_float(a3.y));
        ACC8(w4, __int_as_float(a4.y)); ACC8(w5, __int_as_float(a5.y));
        ACC8(w6, __int_as_float(a6.y)); ACC8(w7, __int_as_float(a7.y));
    }
    for (; i + 4 <= e; i += 4) {
        int2 a0 = edges[i];
        int2 a1 = edges[i + 1];
        int2 a2 = edges[i + 2];
        int2 a3 = edges[i + 3];
        uint4 w0 = hb4[a0.x * 4 + t];
        uint4 w1 = hb4[a1.x * 4 + t];
        uint4 w2 = hb4[a2.x * 4 + t];
        uint4 w3 = hb4[a3.x * 4 + t];
        ACC8(w0, __int_as_float(a0.y)); ACC8(w1, __int_as_float(a1.y));
        ACC8(w2, __int_as_float(a2.y)); ACC8(w3, __int_as_float(a3.y));
    }
    for (; i < e; ++i) {
        int2 a0 = edges[i];
        uint4 w0 = hb4[a0.x * 4 + t];
        ACC8(w0, __int_as_float(a0.y));
    }
#undef ACC8

    // epilogue: lane owns feats [8t, 8t+8)
    if (MODE == 0 || MODE == 1) {
        uint4 p;
        p.x = f2bf(acc[0]) | (f2bf(acc[1]) << 16);
        p.y = f2bf(acc[2]) | (f2bf(acc[3]) << 16);
        p.z = f2bf(acc[4]) | (f2bf(acc[5]) << 16);
        p.w = f2bf(acc[6]) | (f2bf(acc[7]) << 16);
        houtb4[g * 4 + t] = p;
    }
    const int o = g * 8 + t * 2;                 // two float4s per lane
    float4 lo, hi;
    if (MODE == 0) {
        float4 x0 = xin4[o], x1 = xin4[o + 1];
        lo = make_float4(x0.x + acc[0], x0.y + acc[1], x0.z + acc[2], x0.w + acc[3]);
        hi = make_float4(x1.x + acc[4], x1.y + acc[5], x1.z + acc[6], x1.w + acc[7]);
    } else if (MODE == 1) {
        float4 o0 = out4[o], o1 = out4[o + 1];
        lo = make_float4(o0.x + acc[0], o0.y + acc[1], o0.z + acc[2], o0.w + acc[3]);
        hi = make_float4(o1.x + acc[4], o1.y + acc[5], o1.z + acc[6], o1.w + acc[7]);
    } else {
        float4 o0 = out4[o], o1 = out4[o + 1];
        lo = make_float4((o0.x + acc[0]) * 0.25f, (o0.y + acc[1]) * 0.25f,
                         (o0.z + acc[2]) * 0.25f, (o0.w + acc[3]) * 0.25f);
        hi = make_float4((o1.x + acc[4]) * 0.25f, (o1.y + acc[5]) * 0.25f,
                         (o1.z + acc[6]) * 0.25f, (o1.w + acc[7]) * 0.25f);
    }
    out4[o] = lo;
    out4[o + 1] = hi;
}

// ---- launch ---------------------------------------------------------------

extern "C" void kernel_launch(void* const* d_in, const int* in_sizes, int n_in,
                              void* d_out, int out_size, void* d_ws, size_t ws_size,
                              hipStream_t stream) {
    const int*   edge_row = (const int*)d_in[0];
    const int*   edge_col = (const int*)d_in[1];
    const float* edge_val = (const float*)d_in[2];
    const float* x        = (const float*)d_in[3];
    float* out = (float*)d_out;

    char* ws = (char*)d_ws;
    int*  H          = (int*)ws;   ws += (((size_t)NCHUNK * NBKT * 4) + 511) & ~511ull; // 1.22 MB
    int*  P          = (int*)ws;   ws += (((size_t)NCHUNK * NBKT * 4) + 511) & ~511ull; // 1.22 MB
    int*  tot        = (int*)ws;   ws += 4096;
    int*  bucketbase = (int*)ws;   ws += 4096;
    int*  row_ptr    = (int*)ws;   ws += ((size_t)(NN + 1) * 4 + 511) & ~511ull;
    int2* tmp        = (int2*)ws;  ws += (size_t)NE * 8 + 64;   // 12.8 MB
    int2* edges      = (int2*)ws;  ws += (size_t)NE * 8 + 64;   // 12.8 MB
    unsigned* hb0    = (unsigned*)ws;  ws += (size_t)NN * DD * 2;  // 6.4 MB bf16
    unsigned* hb1    = (unsigned*)ws;  ws += (size_t)NN * DD * 2;  // 6.4 MB bf16

    hist_kernel       <<<NCHUNK, 1024, 0, stream>>>(edge_row, H);
    scan_chunks_kernel<<<(NBKT + 127) / 128, 128, 0, stream>>>(H, P, tot);
    scan_buckets_kernel<<<1, 1024, 0, stream>>>(tot, bucketbase, row_ptr);
    scatter_kernel    <<<NCHUNK, 1024, 0, stream>>>(edge_row, edge_col, edge_val,
                                                    bucketbase, P, tmp);
    bucket_sort_kernel<<<NBKT, 512, 0, stream>>>(bucketbase, tmp, row_ptr, edges);
    cvt_kernel        <<<(NN * DD / 2 + 255) / 256, 256, 0, stream>>>(
                        (const float2*)x, hb0);

    dim3 sp_grid((NN + 63) / 64);   // 1563 blocks, 4 lanes/row, 64 rows/block
    spmm_kernel<0><<<sp_grid, 256, 0, stream>>>(row_ptr, edges,
        (const uint4*)hb0, (uint4*)hb1, (const float4*)x, (float4*)out);
    spmm_kernel<1><<<sp_grid, 256, 0, stream>>>(row_ptr, edges,
        (const uint4*)hb1, (uint4*)hb0, (const float4*)x, (float4*)out);
    spmm_kernel<2><<<sp_grid, 256, 0, stream>>>(row_ptr, edges,
        (const uint4*)hb0, (uint4*)hb1, (const float4*)x, (float4*)out);
}

// Round 3
// 195.321 us; speedup vs baseline: 5.7763x; 1.2579x over previous
//
#include <hip/hip_runtime.h>

// LightGCN propagation on MI355X (gfx950).
//   h_{k+1}[r,:] = sum_{e: row[e]==r} val[e] * h_k[col[e],:]   D=32
//   out = (x + h1 + h2 + h3) / 4
//
// Round 12: R11 post-mortem -- atomic-free build worked, but the serial
// scan_chunks kernel (782 threads, 391-long dependent add chain, occupancy
// 0.13%) cost 57.4 us. Replaced with a wave-parallel segmented scan: one
// wave per bucket, 7 shfl-prefix steps over the 391 chunks. Cross-kernel
// layout discipline (per-XCD L2s non-coherent, partial-line multi-XCD
// writes are a hazard): H stays producer-coalesced [c][b]; scan gathers it
// (reads scattered = safe), writes prefix TRANSPOSED Pt[b][c] so each line
// has a single writer wave; scatter gathers Pt[b][chunk] (read = safe).
// hist edge_row load vectorized to int4 (one vector load per thread).

#define NN 100000
#define NE 1600000
#define DD 32
#define CHUNK 4096
#define NCHUNK ((NE + CHUNK - 1) / CHUNK)   // 391
#define BROWS 128
#define NBKT ((NN + BROWS - 1) / BROWS)     // 782

__device__ __forceinline__ unsigned f2bf(float f) {
    unsigned u = __float_as_uint(f);
    return (u + 0x7fffu + ((u >> 16) & 1u)) >> 16;   // RNE
}

// ---- pass 1: per-chunk bucket histogram matrix H[c][b] (coalesced) -------

__global__ __launch_bounds__(1024) void hist_kernel(
    const int* __restrict__ row, int* __restrict__ H)
{
    __shared__ int cnt[NBKT];
    const int tid = threadIdx.x;
    const int start = blockIdx.x * CHUNK;
    const int n = min(CHUNK, NE - start);
    for (int k = tid; k < NBKT; k += 1024) cnt[k] = 0;
    __syncthreads();
    const int j = tid * 4;                       // 4 edges per thread
    if (j + 3 < n) {
        int4 r4 = *(const int4*)(row + start + j);
        atomicAdd(&cnt[r4.x >> 7], 1);
        atomicAdd(&cnt[r4.y >> 7], 1);
        atomicAdd(&cnt[r4.z >> 7], 1);
        atomicAdd(&cnt[r4.w >> 7], 1);
    } else {
        for (int k = j; k < n; k++) atomicAdd(&cnt[row[start + k] >> 7], 1);
    }
    __syncthreads();
    int* Hrow = H + (size_t)blockIdx.x * NBKT;
    for (int k = tid; k < NBKT; k += 1024) Hrow[k] = cnt[k];   // coalesced
}

// ---- pass 2a: wave-parallel per-bucket scan over chunks ------------------
// Wave w of block handles bucket b; lane l covers chunk c0+l. Reads H[c][b]
// (strided gather, read-only), writes Pt[b][c] (contiguous per wave).

__global__ __launch_bounds__(1024) void scan_tr_kernel(
    const int* __restrict__ H, int* __restrict__ Pt, int* __restrict__ tot)
{
    const int b = blockIdx.x * 16 + (threadIdx.x >> 6);
    if (b >= NBKT) return;
    const int lane = threadIdx.x & 63;
    int run = 0;
    #pragma unroll
    for (int c0 = 0; c0 < NCHUNK; c0 += 64) {
        int c = c0 + lane;
        int v = (c < NCHUNK) ? H[(size_t)c * NBKT + b] : 0;
        int x = v;
        #pragma unroll
        for (int off = 1; off < 64; off <<= 1) {
            int y = __shfl_up(x, off, 64);
            if (lane >= off) x += y;
        }
        if (c < NCHUNK) Pt[(size_t)b * NCHUNK + c] = run + x - v;  // exclusive
        run += __shfl(x, 63, 64);                 // wave total
    }
    if (lane == 0) tot[b] = run;
}

// ---- pass 2b: exclusive scan of 782 bucket totals ------------------------

__global__ __launch_bounds__(1024) void scan_buckets_kernel(
    const int* __restrict__ tot, int* __restrict__ bucketbase,
    int* __restrict__ row_ptr)
{
    const int tid = threadIdx.x;
    int v = (tid < NBKT) ? tot[tid] : 0;
    int lane = tid & 63, w = tid >> 6;          // 16 waves
    int x = v;
    #pragma unroll
    for (int off = 1; off < 64; off <<= 1) {
        int y = __shfl_up(x, off, 64);
        if (lane >= off) x += y;
    }
    __shared__ int wt[16];
    if (lane == 63) wt[w] = x;
    __syncthreads();
    if (w == 0 && lane < 16) {
        int y = wt[lane];
        #pragma unroll
        for (int off = 1; off < 16; off <<= 1) {
            int z = __shfl_up(y, off, 16);
            if ((lane & 15) >= off) y += z;
        }
        wt[lane] = y;                            // inclusive wave totals
    }
    __syncthreads();
    int wo = (w > 0) ? wt[w - 1] : 0;
    int excl = x + wo - v;
    if (tid < NBKT) bucketbase[tid] = excl;
    if (tid == NBKT) { bucketbase[NBKT] = NE; row_ptr[NN] = NE; }
}

// ---- pass 3: multisplit scatter, deterministic dest, LDS-staged stores ---
// record: ((row & 127) << 17) | col   (col < 2^17), val bits in .y

__global__ __launch_bounds__(1024) void scatter_kernel(
    const int* __restrict__ row, const int* __restrict__ col,
    const float* __restrict__ val, const int* __restrict__ bucketbase,
    const int* __restrict__ Pt, int2* __restrict__ tmp)
{
    __shared__ int cnt[NBKT];      // 3.1 KB
    __shared__ int lbase[NBKT];    // 3.1 KB  chunk-local exclusive scan
    __shared__ int gofs[NBKT];     // 3.1 KB  global base per bucket
    __shared__ int wt[16];
    __shared__ int2 recs[CHUNK];   // 32 KB   records in bucket order
    __shared__ int dest[CHUNK];    // 16 KB   global dst per sorted position
    const int tid = threadIdx.x;
    const int start = blockIdx.x * CHUNK;
    const int n = min(CHUNK, NE - start);
    for (int k = tid; k < NBKT; k += 1024) cnt[k] = 0;
    __syncthreads();

    int rrow[CHUNK / 1024], rcol[CHUNK / 1024], rank[CHUNK / 1024];
    float rval[CHUNK / 1024];
    #pragma unroll
    for (int k = 0; k < CHUNK / 1024; k++) {
        int j = k * 1024 + tid;
        if (j < n) {
            int r = row[start + j];
            rrow[k] = r;
            rcol[k] = col[start + j];
            rval[k] = val[start + j];
            rank[k] = atomicAdd(&cnt[r >> 7], 1);
        } else {
            rrow[k] = -1;
        }
    }
    __syncthreads();

    // block-level exclusive scan of cnt -> lbase; deterministic gofs
    int v = (tid < NBKT) ? cnt[tid] : 0;
    {
        int lane = tid & 63, w = tid >> 6;
        int x = v;
        #pragma unroll
        for (int off = 1; off < 64; off <<= 1) {
            int y = __shfl_up(x, off, 64);
            if (lane >= off) x += y;
        }
        if (lane == 63) wt[w] = x;
        __syncthreads();
        if (w == 0 && lane < 16) {
            int y = wt[lane];
            #pragma unroll
            for (int off = 1; off < 16; off <<= 1) {
                int z = __shfl_up(y, off, 16);
                if ((lane & 15) >= off) y += z;
            }
            wt[lane] = y;
        }
        __syncthreads();
        int excl = x + ((w > 0) ? wt[w - 1] : 0) - v;
        if (tid < NBKT) {
            lbase[tid] = excl;
            gofs[tid] = bucketbase[tid] + Pt[(size_t)tid * NCHUNK + blockIdx.x];
        }
    }
    __syncthreads();

    #pragma unroll
    for (int k = 0; k < CHUNK / 1024; k++) {
        if (rrow[k] >= 0) {
            int b = rrow[k] >> 7;
            int p = lbase[b] + rank[k];
            recs[p] = make_int2(((rrow[k] & 127) << 17) | rcol[k],
                                __float_as_int(rval[k]));
            dest[p] = gofs[b] + rank[k];
        }
    }
    __syncthreads();

    for (int p = tid; p < n; p += 1024)        // run-contiguous stores
        tmp[dest[p]] = recs[p];
}

// ---- pass 4: per-bucket row sort -> CSR row_ptr + clean (col,val) --------

__global__ __launch_bounds__(512) void bucket_sort_kernel(
    const int* __restrict__ bucketbase, const int2* __restrict__ tmp,
    int* __restrict__ row_ptr, int2* __restrict__ edges)
{
    __shared__ int cnt[BROWS];
    __shared__ int cur[BROWS];
    __shared__ int wt2[2];
    const int tid = threadIdx.x;
    const int b   = blockIdx.x;
    const int s   = bucketbase[b];
    const int e   = bucketbase[b + 1];

    if (tid < BROWS) cnt[tid] = 0;
    __syncthreads();

    int2 rc[5];
    #pragma unroll
    for (int k = 0; k < 5; k++) {
        int j = s + k * 512 + tid;
        rc[k] = (j < e) ? tmp[j] : make_int2(-1, 0);
        if (rc[k].x >= 0) atomicAdd(&cnt[rc[k].x >> 17], 1);
    }
    for (int j = s + 5 * 512 + tid; j < e; j += 512)       // overflow (rare)
        atomicAdd(&cnt[tmp[j].x >> 17], 1);
    __syncthreads();

    int v = 0, x = 0;
    if (tid < BROWS) {
        v = cnt[tid];
        int lane = tid & 63;
        x = v;
        #pragma unroll
        for (int off = 1; off < 64; off <<= 1) {
            int y = __shfl_up(x, off, 64);
            if (lane >= off) x += y;
        }
        if (lane == 63) wt2[tid >> 6] = x;
    }
    __syncthreads();
    if (tid < BROWS) {
        int excl = x + ((tid >> 6) ? wt2[0] : 0) - v;
        cur[tid] = excl;
        int r = b * BROWS + tid;
        if (r < NN) row_ptr[r] = s + excl;
    }
    __syncthreads();

    #pragma unroll
    for (int k = 0; k < 5; k++) {
        if (rc[k].x >= 0) {
            int pos = s + atomicAdd(&cur[rc[k].x >> 17], 1);
            edges[pos] = make_int2(rc[k].x & 0x1FFFF, rc[k].y);
        }
    }
    for (int j = s + 5 * 512 + tid; j < e; j += 512) {     // overflow (rare)
        int2 rec = tmp[j];
        int pos = s + atomicAdd(&cur[rec.x >> 17], 1);
        edges[pos] = make_int2(rec.x & 0x1FFFF, rec.y);
    }
}

// ---- x -> bf16 table (feat 2k in low half, 2k+1 in high half) ------------

__global__ __launch_bounds__(256) void cvt_kernel(
    const float2* __restrict__ xin2, unsigned* __restrict__ hb)
{
    int j = blockIdx.x * 256 + threadIdx.x;      // word index, NN*DD/2 words
    if (j >= NN * DD / 2) return;
    float2 f = xin2[j];
    hb[j] = f2bf(f.x) | (f2bf(f.y) << 16);
}

// ---- SpMM: 4-lane group per row, bf16 gather (64 B row = 1 line) ---------
// Lane t in [0,4) owns feats [8t, 8t+8) = one uint4 of the bf16 row.
// 8 gathers in flight (gather-latency bound: table thrashes 4MB/XCD L2).
// MODE 0: houtb = bf16(A x)  ; out  = x + A x
// MODE 1: houtb = bf16(A h)  ; out += A h
// MODE 2: out = (out + A h) * 0.25

template <int MODE>
__global__ __launch_bounds__(256) void spmm_kernel(
    const int* __restrict__ row_ptr, const int2* __restrict__ edges,
    const uint4* __restrict__ hb4,               // bf16 table, 4 uint4/row
    uint4* __restrict__ houtb4,                  // next bf16 table
    const float4* __restrict__ xin4, float4* __restrict__ out4)
{
    const int g = blockIdx.x * 64 + (threadIdx.x >> 2);   // row
    if (g >= NN) return;
    const int t = threadIdx.x & 3;
    const int s = row_ptr[g];
    const int e = row_ptr[g + 1];

    float acc[8] = {0.f, 0.f, 0.f, 0.f, 0.f, 0.f, 0.f, 0.f};

#define ACC8(W, V)                                                         \
    do {                                                                   \
        acc[0] += (V) * __uint_as_float((W).x << 16);                      \
        acc[1] += (V) * __uint_as_float((W).x & 0xffff0000u);              \
        acc[2] += (V) * __uint_as_float((W).y << 16);                      \
        acc[3] += (V) * __uint_as_float((W).y & 0xffff0000u);              \
        acc[4] += (V) * __uint_as_float((W).z << 16);                      \
        acc[5] += (V) * __uint_as_float((W).z & 0xffff0000u);              \
        acc[6] += (V) * __uint_as_float((W).w << 16);                      \
        acc[7] += (V) * __uint_as_float((W).w & 0xffff0000u);              \
    } while (0)

    int i = s;
    for (; i + 8 <= e; i += 8) {                 // 8 gathers in flight
        int2 a0 = edges[i];
        int2 a1 = edges[i + 1];
        int2 a2 = edges[i + 2];
        int2 a3 = edges[i + 3];
        int2 a4 = edges[i + 4];
        int2 a5 = edges[i + 5];
        int2 a6 = edges[i + 6];
        int2 a7 = edges[i + 7];
        uint4 w0 = hb4[a0.x * 4 + t];
        uint4 w1 = hb4[a1.x * 4 + t];
        uint4 w2 = hb4[a2.x * 4 + t];
        uint4 w3 = hb4[a3.x * 4 + t];
        uint4 w4 = hb4[a4.x * 4 + t];
        uint4 w5 = hb4[a5.x * 4 + t];
        uint4 w6 = hb4[a6.x * 4 + t];
        uint4 w7 = hb4[a7.x * 4 + t];
        ACC8(w0, __int_as_float(a0.y)); ACC8(w1, __int_as_float(a1.y));
        ACC8(w2, __int_as_float(a2.y)); ACC8(w3, __int_as_float(a3.y));
        ACC8(w4, __int_as_float(a4.y)); ACC8(w5, __int_as_float(a5.y));
        ACC8(w6, __int_as_float(a6.y)); ACC8(w7, __int_as_float(a7.y));
    }
    for (; i + 4 <= e; i += 4) {
        int2 a0 = edges[i];
        int2 a1 = edges[i + 1];
        int2 a2 = edges[i + 2];
        int2 a3 = edges[i + 3];
        uint4 w0 = hb4[a0.x * 4 + t];
        uint4 w1 = hb4[a1.x * 4 + t];
        uint4 w2 = hb4[a2.x * 4 + t];
        uint4 w3 = hb4[a3.x * 4 + t];
        ACC8(w0, __int_as_float(a0.y)); ACC8(w1, __int_as_float(a1.y));
        ACC8(w2, __int_as_float(a2.y)); ACC8(w3, __int_as_float(a3.y));
    }
    for (; i < e; ++i) {
        int2 a0 = edges[i];
        uint4 w0 = hb4[a0.x * 4 + t];
        ACC8(w0, __int_as_float(a0.y));
    }
#undef ACC8

    // epilogue: lane owns feats [8t, 8t+8)
    if (MODE == 0 || MODE == 1) {
        uint4 p;
        p.x = f2bf(acc[0]) | (f2bf(acc[1]) << 16);
        p.y = f2bf(acc[2]) | (f2bf(acc[3]) << 16);
        p.z = f2bf(acc[4]) | (f2bf(acc[5]) << 16);
        p.w = f2bf(acc[6]) | (f2bf(acc[7]) << 16);
        houtb4[g * 4 + t] = p;
    }
    const int o = g * 8 + t * 2;                 // two float4s per lane
    float4 lo, hi;
    if (MODE == 0) {
        float4 x0 = xin4[o], x1 = xin4[o + 1];
        lo = make_float4(x0.x + acc[0], x0.y + acc[1], x0.z + acc[2], x0.w + acc[3]);
        hi = make_float4(x1.x + acc[4], x1.y + acc[5], x1.z + acc[6], x1.w + acc[7]);
    } else if (MODE == 1) {
        float4 o0 = out4[o], o1 = out4[o + 1];
        lo = make_float4(o0.x + acc[0], o0.y + acc[1], o0.z + acc[2], o0.w + acc[3]);
        hi = make_float4(o1.x + acc[4], o1.y + acc[5], o1.z + acc[6], o1.w + acc[7]);
    } else {
        float4 o0 = out4[o], o1 = out4[o + 1];
        lo = make_float4((o0.x + acc[0]) * 0.25f, (o0.y + acc[1]) * 0.25f,
                         (o0.z + acc[2]) * 0.25f, (o0.w + acc[3]) * 0.25f);
        hi = make_float4((o1.x + acc[4]) * 0.25f, (o1.y + acc[5]) * 0.25f,
                         (o1.z + acc[6]) * 0.25f, (o1.w + acc[7]) * 0.25f);
    }
    out4[o] = lo;
    out4[o + 1] = hi;
}

// ---- launch ---------------------------------------------------------------

extern "C" void kernel_launch(void* const* d_in, const int* in_sizes, int n_in,
                              void* d_out, int out_size, void* d_ws, size_t ws_size,
                              hipStream_t stream) {
    const int*   edge_row = (const int*)d_in[0];
    const int*   edge_col = (const int*)d_in[1];
    const float* edge_val = (const float*)d_in[2];
    const float* x        = (const float*)d_in[3];
    float* out = (float*)d_out;

    char* ws = (char*)d_ws;
    int*  H          = (int*)ws;   ws += (((size_t)NCHUNK * NBKT * 4) + 511) & ~511ull; // 1.22 MB
    int*  Pt         = (int*)ws;   ws += (((size_t)NBKT * NCHUNK * 4) + 511) & ~511ull; // 1.22 MB
    int*  tot        = (int*)ws;   ws += 4096;
    int*  bucketbase = (int*)ws;   ws += 4096;
    int*  row_ptr    = (int*)ws;   ws += ((size_t)(NN + 1) * 4 + 511) & ~511ull;
    int2* tmp        = (int2*)ws;  ws += (size_t)NE * 8 + 64;   // 12.8 MB
    int2* edges      = (int2*)ws;  ws += (size_t)NE * 8 + 64;   // 12.8 MB
    unsigned* hb0    = (unsigned*)ws;  ws += (size_t)NN * DD * 2;  // 6.4 MB bf16
    unsigned* hb1    = (unsigned*)ws;  ws += (size_t)NN * DD * 2;  // 6.4 MB bf16

    hist_kernel        <<<NCHUNK, 1024, 0, stream>>>(edge_row, H);
    scan_tr_kernel     <<<(NBKT + 15) / 16, 1024, 0, stream>>>(H, Pt, tot);
    scan_buckets_kernel<<<1, 1024, 0, stream>>>(tot, bucketbase, row_ptr);
    scatter_kernel     <<<NCHUNK, 1024, 0, stream>>>(edge_row, edge_col, edge_val,
                                                     bucketbase, Pt, tmp);
    bucket_sort_kernel <<<NBKT, 512, 0, stream>>>(bucketbase, tmp, row_ptr, edges);
    cvt_kernel         <<<(NN * DD / 2 + 255) / 256, 256, 0, stream>>>(
                         (const float2*)x, hb0);

    dim3 sp_grid((NN + 63) / 64);   // 1563 blocks, 4 lanes/row, 64 rows/block
    spmm_kernel<0><<<sp_grid, 256, 0, stream>>>(row_ptr, edges,
        (const uint4*)hb0, (uint4*)hb1, (const float4*)x, (float4*)out);
    spmm_kernel<1><<<sp_grid, 256, 0, stream>>>(row_ptr, edges,
        (const uint4*)hb1, (uint4*)hb0, (const float4*)x, (float4*)out);
    spmm_kernel<2><<<sp_grid, 256, 0, stream>>>(row_ptr, edges,
        (const uint4*)hb0, (uint4*)hb1, (const float4*)x, (float4*)out);
}